// Round 5
// baseline (155.171 us; speedup 1.0000x reference)
//
#include <hip/hip_runtime.h>

// ---- prep: pad x_s rows 10->16 floats (64B, one cache line) and x_t rows 5->8 (32B) ----
__global__ __launch_bounds__(256) void pad_tables(const float* __restrict__ xs,
                                                  const float* __restrict__ xt,
                                                  float* __restrict__ xs_pad,
                                                  float* __restrict__ xt_pad,
                                                  int n_s5, int n_t5) {
    int i = blockIdx.x * 256 + threadIdx.x;
    if (i < n_s5) {            // n_s5 = N_S*5 float2 elements
        int row = i / 5, col = i % 5;
        ((float2*)xs_pad)[row * 8 + col] = ((const float2*)xs)[i];
    }
    if (i < n_t5) {            // n_t5 = N_T*5 float elements
        int row = i / 5, col = i % 5;
        xt_pad[row * 8 + col] = xt[i];
    }
}

// __launch_bounds__(256, 4): 4 waves/EU -> 128-VGPR budget. Plain (256) made the
// compiler cap at 64 VGPRs and spill both edges' state to AGPRs (VALUBusy 70%, r4).
template<bool PADDED>
__global__ __launch_bounds__(256, 4) void edge_mlp(
    const float* __restrict__ xs,   // PADDED: 16-float rows, else 10
    const float* __restrict__ xt,   // PADDED: 8-float rows, else 5
    const int* __restrict__ src,
    const int* __restrict__ tgt,
    const float* __restrict__ ea,
    const float* __restrict__ u,
    const int* __restrict__ be,
    const float* __restrict__ W1,
    const float* __restrict__ b1,
    const float* __restrict__ W2,
    const float* __restrict__ b2,
    float* __restrict__ out, int E)
{
    __shared__ float sUp[16 * 12];    // U' = u @ W1[25:35] + b1, padded rows

    const int t = threadIdx.x;
    if (t < 160) {
        const int b = t / 10, j = t % 10;
        float acc = b1[j];
        #pragma unroll
        for (int k = 0; k < 10; ++k) acc += u[b * 10 + k] * W1[(25 + k) * 10 + j];
        sUp[b * 12 + j] = acc;
    }
    __syncthreads();

    // two edges per lane: e0 = base+t, e1 = base+t+256 (both coalesced per wave)
    const int e0 = blockIdx.x * 512 + t;
    const int e1 = e0 + 256;
    const int c0 = (e0 < E) ? e0 : (E - 1);   // clamp: branch-free loads, guarded stores
    const int c1 = (e1 < E) ? e1 : (E - 1);

    // ---- index loads (start both dependent chains immediately) ----
    const int is0 = src[c0], it0 = tgt[c0], ib0 = be[c0];
    const int is1 = src[c1], it1 = tgt[c1], ib1 = be[c1];

    // ---- gather features for both edges ----
    float f0[25], f1[25];
    if (PADDED) {
        {
            const float4* p = (const float4*)xs + (size_t)is0 * 4;   // one 64B line
            float4 a = p[0], b = p[1];
            float2 c = ((const float2*)xs)[(size_t)is0 * 8 + 4];
            f0[0] = a.x; f0[1] = a.y; f0[2] = a.z; f0[3] = a.w;
            f0[4] = b.x; f0[5] = b.y; f0[6] = b.z; f0[7] = b.w;
            f0[8] = c.x; f0[9] = c.y;
        }
        {
            const float4* p = (const float4*)xs + (size_t)is1 * 4;
            float4 a = p[0], b = p[1];
            float2 c = ((const float2*)xs)[(size_t)is1 * 8 + 4];
            f1[0] = a.x; f1[1] = a.y; f1[2] = a.z; f1[3] = a.w;
            f1[4] = b.x; f1[5] = b.y; f1[6] = b.z; f1[7] = b.w;
            f1[8] = c.x; f1[9] = c.y;
        }
        {
            const float4* q = (const float4*)xt + (size_t)it0 * 2;   // 32B row
            float4 d = q[0];
            float  d4 = xt[(size_t)it0 * 8 + 4];
            f0[10] = d.x; f0[11] = d.y; f0[12] = d.z; f0[13] = d.w; f0[14] = d4;
        }
        {
            const float4* q = (const float4*)xt + (size_t)it1 * 2;
            float4 d = q[0];
            float  d4 = xt[(size_t)it1 * 8 + 4];
            f1[10] = d.x; f1[11] = d.y; f1[12] = d.z; f1[13] = d.w; f1[14] = d4;
        }
    } else {
        const float* ps0 = xs + (size_t)is0 * 10;
        const float* ps1 = xs + (size_t)is1 * 10;
        #pragma unroll
        for (int i = 0; i < 5; ++i) {
            float2 a = *(const float2*)(ps0 + 2 * i);
            float2 b = *(const float2*)(ps1 + 2 * i);
            f0[2 * i] = a.x; f0[2 * i + 1] = a.y;
            f1[2 * i] = b.x; f1[2 * i + 1] = b.y;
        }
        const float* pt0 = xt + (size_t)it0 * 5;
        const float* pt1 = xt + (size_t)it1 * 5;
        #pragma unroll
        for (int i = 0; i < 5; ++i) { f0[10 + i] = pt0[i]; f1[10 + i] = pt1[i]; }
    }
    {
        const float2* pe0 = (const float2*)(ea + (size_t)c0 * 10);
        const float2* pe1 = (const float2*)(ea + (size_t)c1 * 10);
        #pragma unroll
        for (int i = 0; i < 5; ++i) {
            float2 a = pe0[i], b = pe1[i];
            f0[15 + 2 * i] = a.x; f0[16 + 2 * i] = a.y;
            f1[15 + 2 * i] = b.x; f1[16 + 2 * i] = b.y;
        }
    }

    // ---- layer 1: h = U'[ib] + f @ W1[0:25]; one s_load weight stream, two FMA streams ----
    float h0[10], h1[10];
    {
        float4 a = *(const float4*)&sUp[ib0 * 12];
        float4 b = *(const float4*)&sUp[ib0 * 12 + 4];
        float2 c = *(const float2*)&sUp[ib0 * 12 + 8];
        h0[0] = a.x; h0[1] = a.y; h0[2] = a.z; h0[3] = a.w;
        h0[4] = b.x; h0[5] = b.y; h0[6] = b.z; h0[7] = b.w;
        h0[8] = c.x; h0[9] = c.y;
    }
    {
        float4 a = *(const float4*)&sUp[ib1 * 12];
        float4 b = *(const float4*)&sUp[ib1 * 12 + 4];
        float2 c = *(const float2*)&sUp[ib1 * 12 + 8];
        h1[0] = a.x; h1[1] = a.y; h1[2] = a.z; h1[3] = a.w;
        h1[4] = b.x; h1[5] = b.y; h1[6] = b.z; h1[7] = b.w;
        h1[8] = c.x; h1[9] = c.y;
    }
    #pragma unroll
    for (int k = 0; k < 25; ++k) {
        #pragma unroll
        for (int j = 0; j < 10; ++j) {
            const float w = W1[k * 10 + j];   // wave-uniform -> SGPR, shared by both edges
            h0[j] += f0[k] * w;
            h1[j] += f1[k] * w;
        }
    }
    #pragma unroll
    for (int j = 0; j < 10; ++j) {
        h0[j] = (h0[j] >= 0.f) ? h0[j] : 0.1f * h0[j];
        h1[j] = (h1[j] >= 0.f) ? h1[j] : 0.1f * h1[j];
    }

    // ---- layer 2, paired ----
    float o0[10], o1[10];
    #pragma unroll
    for (int j = 0; j < 10; ++j) { const float b2j = b2[j]; o0[j] = b2j; o1[j] = b2j; }
    #pragma unroll
    for (int k = 0; k < 10; ++k) {
        #pragma unroll
        for (int j = 0; j < 10; ++j) {
            const float w = W2[k * 10 + j];
            o0[j] += h0[k] * w;
            o1[j] += h1[k] * w;
        }
    }

    // ---- stores (guarded) ----
    if (e0 < E) {
        float2* po = (float2*)(out + (size_t)e0 * 10);
        #pragma unroll
        for (int i = 0; i < 5; ++i) { float2 v; v.x = o0[2 * i]; v.y = o0[2 * i + 1]; po[i] = v; }
    }
    if (e1 < E) {
        float2* po = (float2*)(out + (size_t)e1 * 10);
        #pragma unroll
        for (int i = 0; i < 5; ++i) { float2 v; v.x = o1[2 * i]; v.y = o1[2 * i + 1]; po[i] = v; }
    }
}

extern "C" void kernel_launch(void* const* d_in, const int* in_sizes, int n_in,
                              void* d_out, int out_size, void* d_ws, size_t ws_size,
                              hipStream_t stream) {
    const float* x_s      = (const float*)d_in[0];
    const float* x_t      = (const float*)d_in[1];
    const int*   ei       = (const int*)d_in[2];    // (2, E) flat: [src | tgt]
    const float* edge_att = (const float*)d_in[3];
    const float* u        = (const float*)d_in[4];
    const int*   batch_e  = (const int*)d_in[5];
    const float* W1       = (const float*)d_in[6];
    const float* b1       = (const float*)d_in[7];
    const float* W2       = (const float*)d_in[8];
    const float* b2       = (const float*)d_in[9];
    float* out = (float*)d_out;

    const int E   = in_sizes[5];
    const int N_S = in_sizes[0] / 10;
    const int N_T = in_sizes[1] / 5;
    const int blocks = (E + 511) / 512;   // 2 edges per thread

    const size_t need = (size_t)N_S * 16 * 4 + (size_t)N_T * 8 * 4;
    if (ws_size >= need) {
        float* xs_pad = (float*)d_ws;
        float* xt_pad = (float*)d_ws + (size_t)N_S * 16;
        const int n_s5 = N_S * 5;
        const int n_t5 = N_T * 5;
        const int n    = (n_s5 > n_t5 ? n_s5 : n_t5);
        pad_tables<<<(n + 255) / 256, 256, 0, stream>>>(x_s, x_t, xs_pad, xt_pad, n_s5, n_t5);
        edge_mlp<true><<<blocks, 256, 0, stream>>>(
            xs_pad, xt_pad, ei, ei + E, edge_att, u, batch_e,
            W1, b1, W2, b2, out, E);
    } else {
        edge_mlp<false><<<blocks, 256, 0, stream>>>(
            x_s, x_t, ei, ei + E, edge_att, u, batch_e,
            W1, b1, W2, b2, out, E);
    }
}

// Round 6
// 148.669 us; speedup vs baseline: 1.0437x; 1.0437x over previous
//
#include <hip/hip_runtime.h>
#include <hip/hip_fp16.h>

typedef float f2v __attribute__((ext_vector_type(2)));

// ---- prep: A_s[n] = x_s[n] @ W1[0:10,:]  -> f16, 16-elem (32B) rows ----
__global__ __launch_bounds__(256) void prep_as(const float* __restrict__ xs,
                                               const float* __restrict__ W1,
                                               __half* __restrict__ As, int N) {
    const int n = blockIdx.x * 256 + threadIdx.x;
    if (n >= N) return;
    float f[10];
    const float2* p = (const float2*)(xs + (size_t)n * 10);
    #pragma unroll
    for (int i = 0; i < 5; ++i) { float2 v = p[i]; f[2 * i] = v.x; f[2 * i + 1] = v.y; }
    float a[10];
    #pragma unroll
    for (int j = 0; j < 10; ++j) a[j] = 0.f;
    #pragma unroll
    for (int k = 0; k < 10; ++k) {
        const float fk = f[k];
        #pragma unroll
        for (int j = 0; j < 10; ++j) a[j] += fk * W1[k * 10 + j];   // uniform -> s_load
    }
    __half* dst = As + (size_t)n * 16;
    #pragma unroll
    for (int j = 0; j < 10; ++j) dst[j] = __float2half(a[j]);
}

// ---- prep: A_t[n] = x_t[n] @ W1[10:15,:] -> f16, 16-elem (32B) rows ----
__global__ __launch_bounds__(256) void prep_at(const float* __restrict__ xt,
                                               const float* __restrict__ W1,
                                               __half* __restrict__ At, int N) {
    const int n = blockIdx.x * 256 + threadIdx.x;
    if (n >= N) return;
    float f[5];
    #pragma unroll
    for (int i = 0; i < 5; ++i) f[i] = xt[(size_t)n * 5 + i];
    float a[10];
    #pragma unroll
    for (int j = 0; j < 10; ++j) a[j] = 0.f;
    #pragma unroll
    for (int k = 0; k < 5; ++k) {
        const float fk = f[k];
        #pragma unroll
        for (int j = 0; j < 10; ++j) a[j] += fk * W1[(10 + k) * 10 + j];
    }
    __half* dst = At + (size_t)n * 16;
    #pragma unroll
    for (int j = 0; j < 10; ++j) dst[j] = __float2half(a[j]);
}

// ---- main: h = As[src] + At[tgt] + ea@W1[15:25] + U'[be]; LeakyReLU; @W2+b2 ----
__global__ __launch_bounds__(256) void edge_mlp_pre(
    const __half* __restrict__ As,
    const __half* __restrict__ At,
    const int* __restrict__ src,
    const int* __restrict__ tgt,
    const float* __restrict__ ea,
    const float* __restrict__ u,
    const int* __restrict__ be,
    const float* __restrict__ W1,
    const float* __restrict__ b1,
    const float* __restrict__ W2,
    const float* __restrict__ b2,
    float* __restrict__ out, int E)
{
    __shared__ float sUp[16 * 12];    // U' = u @ W1[25:35] + b1

    const int t = threadIdx.x;
    if (t < 160) {
        const int b = t / 10, j = t % 10;
        float acc = b1[j];
        #pragma unroll
        for (int k = 0; k < 10; ++k) acc += u[b * 10 + k] * W1[(25 + k) * 10 + j];
        sUp[b * 12 + j] = acc;
    }
    __syncthreads();

    const int e = blockIdx.x * 256 + t;
    if (e >= E) return;

    // streaming loads: non-temporal (keep L2 for the gather tables)
    const int is = __builtin_nontemporal_load(src + e);
    const int it = __builtin_nontemporal_load(tgt + e);
    const int ib = __builtin_nontemporal_load(be + e);

    // gathers: one 64B line each (32B-aligned 16-half rows), cached (temporal)
    const __half2* pa = (const __half2*)(As + (size_t)is * 16);
    const __half2* pb = (const __half2*)(At + (size_t)it * 16);
    __half2 av[5], bv[5];
    #pragma unroll
    for (int i = 0; i < 5; ++i) { av[i] = pa[i]; bv[i] = pb[i]; }

    // edge_attr: streaming, non-temporal
    float g[10];
    {
        const f2v* pe = (const f2v*)(ea + (size_t)e * 10);
        #pragma unroll
        for (int i = 0; i < 5; ++i) {
            f2v v = __builtin_nontemporal_load(pe + i);
            g[2 * i] = v[0]; g[2 * i + 1] = v[1];
        }
    }

    // h = As + At + U'  then += ea @ W1[15:25]
    float h[10];
    #pragma unroll
    for (int i = 0; i < 5; ++i) {
        const float2 a2 = __half22float2(av[i]);
        const float2 b2f = __half22float2(bv[i]);
        h[2 * i]     = a2.x + b2f.x + sUp[ib * 12 + 2 * i];
        h[2 * i + 1] = a2.y + b2f.y + sUp[ib * 12 + 2 * i + 1];
    }
    #pragma unroll
    for (int k = 0; k < 10; ++k) {
        const float gk = g[k];
        #pragma unroll
        for (int j = 0; j < 10; ++j) h[j] += gk * W1[(15 + k) * 10 + j];  // s_load stream
    }
    #pragma unroll
    for (int j = 0; j < 10; ++j) h[j] = (h[j] >= 0.f) ? h[j] : 0.1f * h[j];

    // layer 2
    float o[10];
    #pragma unroll
    for (int j = 0; j < 10; ++j) o[j] = b2[j];
    #pragma unroll
    for (int k = 0; k < 10; ++k) {
        const float hk = h[k];
        #pragma unroll
        for (int j = 0; j < 10; ++j) o[j] += hk * W2[k * 10 + j];
    }

    // store: non-temporal float2
    f2v* po = (f2v*)(out + (size_t)e * 10);
    #pragma unroll
    for (int i = 0; i < 5; ++i) {
        f2v v; v[0] = o[2 * i]; v[1] = o[2 * i + 1];
        __builtin_nontemporal_store(v, po + i);
    }
}

// ---- fallback (ws too small): r3-style direct compute from raw tables ----
__global__ __launch_bounds__(256) void edge_mlp_raw(
    const float* __restrict__ xs, const float* __restrict__ xt,
    const int* __restrict__ src, const int* __restrict__ tgt,
    const float* __restrict__ ea, const float* __restrict__ u,
    const int* __restrict__ be,
    const float* __restrict__ W1, const float* __restrict__ b1,
    const float* __restrict__ W2, const float* __restrict__ b2,
    float* __restrict__ out, int E)
{
    __shared__ float sUp[16 * 12];
    const int t = threadIdx.x;
    if (t < 160) {
        const int b = t / 10, j = t % 10;
        float acc = b1[j];
        #pragma unroll
        for (int k = 0; k < 10; ++k) acc += u[b * 10 + k] * W1[(25 + k) * 10 + j];
        sUp[b * 12 + j] = acc;
    }
    __syncthreads();
    const int e = blockIdx.x * 256 + t;
    if (e >= E) return;
    const int is = src[e], it = tgt[e], ib = be[e];
    float f[25];
    const float* ps = xs + (size_t)is * 10;
    #pragma unroll
    for (int i = 0; i < 5; ++i) {
        float2 v = *(const float2*)(ps + 2 * i);
        f[2 * i] = v.x; f[2 * i + 1] = v.y;
    }
    const float* pt = xt + (size_t)it * 5;
    #pragma unroll
    for (int i = 0; i < 5; ++i) f[10 + i] = pt[i];
    const float2* pe = (const float2*)(ea + (size_t)e * 10);
    #pragma unroll
    for (int i = 0; i < 5; ++i) { float2 v = pe[i]; f[15 + 2 * i] = v.x; f[16 + 2 * i] = v.y; }
    float h[10];
    #pragma unroll
    for (int j = 0; j < 10; ++j) h[j] = sUp[ib * 12 + j];
    #pragma unroll
    for (int k = 0; k < 25; ++k) {
        const float fk = f[k];
        #pragma unroll
        for (int j = 0; j < 10; ++j) h[j] += fk * W1[k * 10 + j];
    }
    #pragma unroll
    for (int j = 0; j < 10; ++j) h[j] = (h[j] >= 0.f) ? h[j] : 0.1f * h[j];
    float o[10];
    #pragma unroll
    for (int j = 0; j < 10; ++j) o[j] = b2[j];
    #pragma unroll
    for (int k = 0; k < 10; ++k) {
        const float hk = h[k];
        #pragma unroll
        for (int j = 0; j < 10; ++j) o[j] += hk * W2[k * 10 + j];
    }
    float2* po = (float2*)(out + (size_t)e * 10);
    #pragma unroll
    for (int i = 0; i < 5; ++i) { float2 v; v.x = o[2 * i]; v.y = o[2 * i + 1]; po[i] = v; }
}

extern "C" void kernel_launch(void* const* d_in, const int* in_sizes, int n_in,
                              void* d_out, int out_size, void* d_ws, size_t ws_size,
                              hipStream_t stream) {
    const float* x_s      = (const float*)d_in[0];
    const float* x_t      = (const float*)d_in[1];
    const int*   ei       = (const int*)d_in[2];    // (2, E) flat: [src | tgt]
    const float* edge_att = (const float*)d_in[3];
    const float* u        = (const float*)d_in[4];
    const int*   batch_e  = (const int*)d_in[5];
    const float* W1       = (const float*)d_in[6];
    const float* b1       = (const float*)d_in[7];
    const float* W2       = (const float*)d_in[8];
    const float* b2       = (const float*)d_in[9];
    float* out = (float*)d_out;

    const int E   = in_sizes[5];
    const int N_S = in_sizes[0] / 10;
    const int N_T = in_sizes[1] / 5;
    const int blocks = (E + 255) / 256;

    const size_t need = (size_t)N_S * 16 * sizeof(__half) + (size_t)N_T * 16 * sizeof(__half);
    if (ws_size >= need) {
        __half* As = (__half*)d_ws;
        __half* At = As + (size_t)N_S * 16;
        prep_as<<<(N_S + 255) / 256, 256, 0, stream>>>(x_s, W1, As, N_S);
        prep_at<<<(N_T + 255) / 256, 256, 0, stream>>>(x_t, W1, At, N_T);
        edge_mlp_pre<<<blocks, 256, 0, stream>>>(
            As, At, ei, ei + E, edge_att, u, batch_e,
            W1, b1, W2, b2, out, E);
    } else {
        edge_mlp_raw<<<blocks, 256, 0, stream>>>(
            x_s, x_t, ei, ei + E, edge_att, u, batch_e,
            W1, b1, W2, b2, out, E);
    }
}

// Round 7
// 145.010 us; speedup vs baseline: 1.0701x; 1.0252x over previous
//
#include <hip/hip_runtime.h>
#include <hip/hip_fp16.h>

typedef float f2v __attribute__((ext_vector_type(2)));

// 24B packed row: 10 x f16 (20B) + 4B pad, 8B-aligned. Both tables total 4.8MB -> ~L2-resident.
struct __attribute__((packed, aligned(8))) Row24 {
    uint2 ab;   // h0..h3
    uint2 cd;   // h4..h7
    uint  e;    // h8..h9
    uint  pad;
};

__device__ __forceinline__ float2 h2f2(uint v) {
    __half2 h = *(__half2*)&v;
    return __half22float2(h);
}

// ---- prep: A_s[n] = x_s[n] @ W1[0:10,:]  -> f16 Row24 ----
__global__ __launch_bounds__(256) void prep_as(const float* __restrict__ xs,
                                               const float* __restrict__ W1,
                                               Row24* __restrict__ As, int N) {
    const int n = blockIdx.x * 256 + threadIdx.x;
    if (n >= N) return;
    float f[10];
    const float2* p = (const float2*)(xs + (size_t)n * 10);
    #pragma unroll
    for (int i = 0; i < 5; ++i) { float2 v = p[i]; f[2 * i] = v.x; f[2 * i + 1] = v.y; }
    float a[10];
    #pragma unroll
    for (int j = 0; j < 10; ++j) a[j] = 0.f;
    #pragma unroll
    for (int k = 0; k < 10; ++k) {
        const float fk = f[k];
        #pragma unroll
        for (int j = 0; j < 10; ++j) a[j] += fk * W1[k * 10 + j];   // uniform -> s_load
    }
    uint q[5];
    #pragma unroll
    for (int i = 0; i < 5; ++i) {
        __half2 h = __floats2half2_rn(a[2 * i], a[2 * i + 1]);
        q[i] = *(uint*)&h;
    }
    Row24 r;
    r.ab = make_uint2(q[0], q[1]);
    r.cd = make_uint2(q[2], q[3]);
    r.e  = q[4];
    r.pad = 0;
    As[n] = r;
}

// ---- prep: A_t[n] = x_t[n] @ W1[10:15,:] -> f16 Row24 ----
__global__ __launch_bounds__(256) void prep_at(const float* __restrict__ xt,
                                               const float* __restrict__ W1,
                                               Row24* __restrict__ At, int N) {
    const int n = blockIdx.x * 256 + threadIdx.x;
    if (n >= N) return;
    float f[5];
    #pragma unroll
    for (int i = 0; i < 5; ++i) f[i] = xt[(size_t)n * 5 + i];
    float a[10];
    #pragma unroll
    for (int j = 0; j < 10; ++j) a[j] = 0.f;
    #pragma unroll
    for (int k = 0; k < 5; ++k) {
        const float fk = f[k];
        #pragma unroll
        for (int j = 0; j < 10; ++j) a[j] += fk * W1[(10 + k) * 10 + j];
    }
    uint q[5];
    #pragma unroll
    for (int i = 0; i < 5; ++i) {
        __half2 h = __floats2half2_rn(a[2 * i], a[2 * i + 1]);
        q[i] = *(uint*)&h;
    }
    Row24 r;
    r.ab = make_uint2(q[0], q[1]);
    r.cd = make_uint2(q[2], q[3]);
    r.e  = q[4];
    r.pad = 0;
    At[n] = r;
}

// ---- main: h = As[src] + At[tgt] + ea@W1[15:25] + U'[be]; LeakyReLU; @W2+b2 ----
__global__ __launch_bounds__(256) void edge_mlp_pre(
    const Row24* __restrict__ As,
    const Row24* __restrict__ At,
    const int* __restrict__ src,
    const int* __restrict__ tgt,
    const float* __restrict__ ea,
    const float* __restrict__ u,
    const int* __restrict__ be,
    const float* __restrict__ W1,
    const float* __restrict__ b1,
    const float* __restrict__ W2,
    const float* __restrict__ b2,
    float* __restrict__ out, int E)
{
    __shared__ float sUp[16 * 12];    // U' = u @ W1[25:35] + b1

    const int t = threadIdx.x;
    if (t < 160) {
        const int b = t / 10, j = t % 10;
        float acc = b1[j];
        #pragma unroll
        for (int k = 0; k < 10; ++k) acc += u[b * 10 + k] * W1[(25 + k) * 10 + j];
        sUp[b * 12 + j] = acc;
    }
    __syncthreads();

    const int e = blockIdx.x * 256 + t;
    if (e >= E) return;

    // streaming loads: non-temporal (keep L2 for the gather tables)
    const int is = __builtin_nontemporal_load(src + e);
    const int it = __builtin_nontemporal_load(tgt + e);
    const int ib = __builtin_nontemporal_load(be + e);

    // gathers: 20B payload in a 24B row, temporal (want these resident in L2)
    Row24 ra = As[is];
    Row24 rb = At[it];

    // edge_attr: streaming, non-temporal
    float g[10];
    {
        const f2v* pe = (const f2v*)(ea + (size_t)e * 10);
        #pragma unroll
        for (int i = 0; i < 5; ++i) {
            f2v v = __builtin_nontemporal_load(pe + i);
            g[2 * i] = v[0]; g[2 * i + 1] = v[1];
        }
    }

    // h = As + At + U'
    float h[10];
    {
        uint qa[5] = { ra.ab.x, ra.ab.y, ra.cd.x, ra.cd.y, ra.e };
        uint qb[5] = { rb.ab.x, rb.ab.y, rb.cd.x, rb.cd.y, rb.e };
        #pragma unroll
        for (int i = 0; i < 5; ++i) {
            float2 a2 = h2f2(qa[i]);
            float2 b2f = h2f2(qb[i]);
            h[2 * i]     = a2.x + b2f.x + sUp[ib * 12 + 2 * i];
            h[2 * i + 1] = a2.y + b2f.y + sUp[ib * 12 + 2 * i + 1];
        }
    }
    // += ea @ W1[15:25]
    #pragma unroll
    for (int k = 0; k < 10; ++k) {
        const float gk = g[k];
        #pragma unroll
        for (int j = 0; j < 10; ++j) h[j] += gk * W1[(15 + k) * 10 + j];  // s_load stream
    }
    #pragma unroll
    for (int j = 0; j < 10; ++j) h[j] = (h[j] >= 0.f) ? h[j] : 0.1f * h[j];

    // layer 2
    float o[10];
    #pragma unroll
    for (int j = 0; j < 10; ++j) o[j] = b2[j];
    #pragma unroll
    for (int k = 0; k < 10; ++k) {
        const float hk = h[k];
        #pragma unroll
        for (int j = 0; j < 10; ++j) o[j] += hk * W2[k * 10 + j];
    }

    // store: normal (temporal) float2 -> L2 write-back combines to full lines (r1-r5: WRITE=125MB exact)
    float2* po = (float2*)(out + (size_t)e * 10);
    #pragma unroll
    for (int i = 0; i < 5; ++i) {
        float2 v; v.x = o[2 * i]; v.y = o[2 * i + 1];
        po[i] = v;
    }
}

// ---- fallback (ws too small): direct compute from raw tables ----
__global__ __launch_bounds__(256) void edge_mlp_raw(
    const float* __restrict__ xs, const float* __restrict__ xt,
    const int* __restrict__ src, const int* __restrict__ tgt,
    const float* __restrict__ ea, const float* __restrict__ u,
    const int* __restrict__ be,
    const float* __restrict__ W1, const float* __restrict__ b1,
    const float* __restrict__ W2, const float* __restrict__ b2,
    float* __restrict__ out, int E)
{
    __shared__ float sUp[16 * 12];
    const int t = threadIdx.x;
    if (t < 160) {
        const int b = t / 10, j = t % 10;
        float acc = b1[j];
        #pragma unroll
        for (int k = 0; k < 10; ++k) acc += u[b * 10 + k] * W1[(25 + k) * 10 + j];
        sUp[b * 12 + j] = acc;
    }
    __syncthreads();
    const int e = blockIdx.x * 256 + t;
    if (e >= E) return;
    const int is = src[e], it = tgt[e], ib = be[e];
    float f[25];
    const float* ps = xs + (size_t)is * 10;
    #pragma unroll
    for (int i = 0; i < 5; ++i) {
        float2 v = *(const float2*)(ps + 2 * i);
        f[2 * i] = v.x; f[2 * i + 1] = v.y;
    }
    const float* pt = xt + (size_t)it * 5;
    #pragma unroll
    for (int i = 0; i < 5; ++i) f[10 + i] = pt[i];
    const float2* pe = (const float2*)(ea + (size_t)e * 10);
    #pragma unroll
    for (int i = 0; i < 5; ++i) { float2 v = pe[i]; f[15 + 2 * i] = v.x; f[16 + 2 * i] = v.y; }
    float h[10];
    #pragma unroll
    for (int j = 0; j < 10; ++j) h[j] = sUp[ib * 12 + j];
    #pragma unroll
    for (int k = 0; k < 25; ++k) {
        const float fk = f[k];
        #pragma unroll
        for (int j = 0; j < 10; ++j) h[j] += fk * W1[k * 10 + j];
    }
    #pragma unroll
    for (int j = 0; j < 10; ++j) h[j] = (h[j] >= 0.f) ? h[j] : 0.1f * h[j];
    float o[10];
    #pragma unroll
    for (int j = 0; j < 10; ++j) o[j] = b2[j];
    #pragma unroll
    for (int k = 0; k < 10; ++k) {
        const float hk = h[k];
        #pragma unroll
        for (int j = 0; j < 10; ++j) o[j] += hk * W2[k * 10 + j];
    }
    float2* po = (float2*)(out + (size_t)e * 10);
    #pragma unroll
    for (int i = 0; i < 5; ++i) { float2 v; v.x = o[2 * i]; v.y = o[2 * i + 1]; po[i] = v; }
}

extern "C" void kernel_launch(void* const* d_in, const int* in_sizes, int n_in,
                              void* d_out, int out_size, void* d_ws, size_t ws_size,
                              hipStream_t stream) {
    const float* x_s      = (const float*)d_in[0];
    const float* x_t      = (const float*)d_in[1];
    const int*   ei       = (const int*)d_in[2];    // (2, E) flat: [src | tgt]
    const float* edge_att = (const float*)d_in[3];
    const float* u        = (const float*)d_in[4];
    const int*   batch_e  = (const int*)d_in[5];
    const float* W1       = (const float*)d_in[6];
    const float* b1       = (const float*)d_in[7];
    const float* W2       = (const float*)d_in[8];
    const float* b2       = (const float*)d_in[9];
    float* out = (float*)d_out;

    const int E   = in_sizes[5];
    const int N_S = in_sizes[0] / 10;
    const int N_T = in_sizes[1] / 5;
    const int blocks = (E + 255) / 256;

    const size_t need = ((size_t)N_S + (size_t)N_T) * sizeof(Row24);
    if (ws_size >= need) {
        Row24* As = (Row24*)d_ws;
        Row24* At = As + N_S;
        prep_as<<<(N_S + 255) / 256, 256, 0, stream>>>(x_s, W1, As, N_S);
        prep_at<<<(N_T + 255) / 256, 256, 0, stream>>>(x_t, W1, At, N_T);
        edge_mlp_pre<<<blocks, 256, 0, stream>>>(
            As, At, ei, ei + E, edge_att, u, batch_e,
            W1, b1, W2, b2, out, E);
    } else {
        edge_mlp_raw<<<blocks, 256, 0, stream>>>(
            x_s, x_t, ei, ei + E, edge_att, u, batch_e,
            W1, b1, W2, b2, out, E);
    }
}

// Round 8
// 132.884 us; speedup vs baseline: 1.1677x; 1.0913x over previous
//
#include <hip/hip_runtime.h>
#include <hip/hip_fp16.h>

typedef float f2v __attribute__((ext_vector_type(2)));

// 24B packed row: 10 x f16 (20B) + 4B pad, 8B-aligned. As table = 2.4MB.
struct __attribute__((packed, aligned(8))) Row24 {
    uint2 ab;   // h0..h3
    uint2 cd;   // h4..h7
    uint  e;    // h8..h9
    uint  pad;
};

__device__ __forceinline__ float2 h2f2(uint v) {
    __half2 h = *(__half2*)&v;
    return __half22float2(h);
}

// ---- prep: A_s[n] = x_s[n] @ W1[0:10,:]  -> f16 Row24 (2.4 MB) ----
__global__ __launch_bounds__(256) void prep_as(const float* __restrict__ xs,
                                               const float* __restrict__ W1,
                                               Row24* __restrict__ As, int N) {
    const int n = blockIdx.x * 256 + threadIdx.x;
    if (n >= N) return;
    float f[10];
    const float2* p = (const float2*)(xs + (size_t)n * 10);
    #pragma unroll
    for (int i = 0; i < 5; ++i) { float2 v = p[i]; f[2 * i] = v.x; f[2 * i + 1] = v.y; }
    float a[10];
    #pragma unroll
    for (int j = 0; j < 10; ++j) a[j] = 0.f;
    #pragma unroll
    for (int k = 0; k < 10; ++k) {
        const float fk = f[k];
        #pragma unroll
        for (int j = 0; j < 10; ++j) a[j] += fk * W1[k * 10 + j];   // uniform -> s_load
    }
    uint q[5];
    #pragma unroll
    for (int i = 0; i < 5; ++i) {
        __half2 h = __floats2half2_rn(a[2 * i], a[2 * i + 1]);
        q[i] = *(uint*)&h;
    }
    Row24 r;
    r.ab = make_uint2(q[0], q[1]);
    r.cd = make_uint2(q[2], q[3]);
    r.e  = q[4];
    r.pad = 0;
    As[n] = r;
}

// ---- prep: x_t[n] -> 5 x f16 packed into 16B (one dwordx4 gather; 1.6 MB) ----
__global__ __launch_bounds__(256) void prep_xt(const float* __restrict__ xt,
                                               uint4* __restrict__ Xt, int N) {
    const int n = blockIdx.x * 256 + threadIdx.x;
    if (n >= N) return;
    float f[5];
    #pragma unroll
    for (int i = 0; i < 5; ++i) f[i] = xt[(size_t)n * 5 + i];
    __half2 h01 = __floats2half2_rn(f[0], f[1]);
    __half2 h23 = __floats2half2_rn(f[2], f[3]);
    __half2 h4_ = __floats2half2_rn(f[4], 0.f);
    uint4 r;
    r.x = *(uint*)&h01;
    r.y = *(uint*)&h23;
    r.z = *(uint*)&h4_;
    r.w = 0;
    Xt[n] = r;
}

// ---- main: h = As[src] + xt16[tgt]@W1[10:15] + ea@W1[15:25] + U'[be]; LReLU; @W2+b2 ----
__global__ __launch_bounds__(256) void edge_mlp_pre(
    const Row24* __restrict__ As,
    const uint4* __restrict__ Xt,
    const int* __restrict__ src,
    const int* __restrict__ tgt,
    const float* __restrict__ ea,
    const float* __restrict__ u,
    const int* __restrict__ be,
    const float* __restrict__ W1,
    const float* __restrict__ b1,
    const float* __restrict__ W2,
    const float* __restrict__ b2,
    float* __restrict__ out, int E)
{
    __shared__ float sUp[16 * 12];    // U' = u @ W1[25:35] + b1

    const int t = threadIdx.x;
    if (t < 160) {
        const int b = t / 10, j = t % 10;
        float acc = b1[j];
        #pragma unroll
        for (int k = 0; k < 10; ++k) acc += u[b * 10 + k] * W1[(25 + k) * 10 + j];
        sUp[b * 12 + j] = acc;
    }
    __syncthreads();

    const int e = blockIdx.x * 256 + t;
    if (e >= E) return;

    // streaming loads: non-temporal (keep L2 for the gather tables)
    const int is = __builtin_nontemporal_load(src + e);
    const int it = __builtin_nontemporal_load(tgt + e);
    const int ib = __builtin_nontemporal_load(be + e);

    // gathers (temporal; 4.0 MB combined working set, 3 VMEM instrs total)
    Row24 ra = As[is];            // dwordx4 + dwordx2
    uint4 rt = Xt[it];            // dwordx4

    // edge_attr: streaming, non-temporal
    float g[10];
    {
        const f2v* pe = (const f2v*)(ea + (size_t)e * 10);
        #pragma unroll
        for (int i = 0; i < 5; ++i) {
            f2v v = __builtin_nontemporal_load(pe + i);
            g[2 * i] = v[0]; g[2 * i + 1] = v[1];
        }
    }

    // h = As + U'
    float h[10];
    {
        uint qa[5] = { ra.ab.x, ra.ab.y, ra.cd.x, ra.cd.y, ra.e };
        #pragma unroll
        for (int i = 0; i < 5; ++i) {
            float2 a2 = h2f2(qa[i]);
            h[2 * i]     = a2.x + sUp[ib * 12 + 2 * i];
            h[2 * i + 1] = a2.y + sUp[ib * 12 + 2 * i + 1];
        }
    }
    // += x_t @ W1[10:15]  (5 values, SGPR weights)
    {
        float2 t01 = h2f2(rt.x);
        float2 t23 = h2f2(rt.y);
        float2 t4_ = h2f2(rt.z);
        const float tv[5] = { t01.x, t01.y, t23.x, t23.y, t4_.x };
        #pragma unroll
        for (int k = 0; k < 5; ++k) {
            const float fk = tv[k];
            #pragma unroll
            for (int j = 0; j < 10; ++j) h[j] += fk * W1[(10 + k) * 10 + j];
        }
    }
    // += ea @ W1[15:25]
    #pragma unroll
    for (int k = 0; k < 10; ++k) {
        const float gk = g[k];
        #pragma unroll
        for (int j = 0; j < 10; ++j) h[j] += gk * W1[(15 + k) * 10 + j];
    }
    #pragma unroll
    for (int j = 0; j < 10; ++j) h[j] = (h[j] >= 0.f) ? h[j] : 0.1f * h[j];

    // layer 2
    float o[10];
    #pragma unroll
    for (int j = 0; j < 10; ++j) o[j] = b2[j];
    #pragma unroll
    for (int k = 0; k < 10; ++k) {
        const float hk = h[k];
        #pragma unroll
        for (int j = 0; j < 10; ++j) o[j] += hk * W2[k * 10 + j];
    }

    // store: temporal float2 (write-combines to full lines; WRITE=125MB exact)
    float2* po = (float2*)(out + (size_t)e * 10);
    #pragma unroll
    for (int i = 0; i < 5; ++i) {
        float2 v; v.x = o[2 * i]; v.y = o[2 * i + 1];
        po[i] = v;
    }
}

// ---- fallback (ws too small): direct compute from raw tables ----
__global__ __launch_bounds__(256) void edge_mlp_raw(
    const float* __restrict__ xs, const float* __restrict__ xt,
    const int* __restrict__ src, const int* __restrict__ tgt,
    const float* __restrict__ ea, const float* __restrict__ u,
    const int* __restrict__ be,
    const float* __restrict__ W1, const float* __restrict__ b1,
    const float* __restrict__ W2, const float* __restrict__ b2,
    float* __restrict__ out, int E)
{
    __shared__ float sUp[16 * 12];
    const int t = threadIdx.x;
    if (t < 160) {
        const int b = t / 10, j = t % 10;
        float acc = b1[j];
        #pragma unroll
        for (int k = 0; k < 10; ++k) acc += u[b * 10 + k] * W1[(25 + k) * 10 + j];
        sUp[b * 12 + j] = acc;
    }
    __syncthreads();
    const int e = blockIdx.x * 256 + t;
    if (e >= E) return;
    const int is = src[e], it = tgt[e], ib = be[e];
    float f[25];
    const float* ps = xs + (size_t)is * 10;
    #pragma unroll
    for (int i = 0; i < 5; ++i) {
        float2 v = *(const float2*)(ps + 2 * i);
        f[2 * i] = v.x; f[2 * i + 1] = v.y;
    }
    const float* pt = xt + (size_t)it * 5;
    #pragma unroll
    for (int i = 0; i < 5; ++i) f[10 + i] = pt[i];
    const float2* pe = (const float2*)(ea + (size_t)e * 10);
    #pragma unroll
    for (int i = 0; i < 5; ++i) { float2 v = pe[i]; f[15 + 2 * i] = v.x; f[16 + 2 * i] = v.y; }
    float h[10];
    #pragma unroll
    for (int j = 0; j < 10; ++j) h[j] = sUp[ib * 12 + j];
    #pragma unroll
    for (int k = 0; k < 25; ++k) {
        const float fk = f[k];
        #pragma unroll
        for (int j = 0; j < 10; ++j) h[j] += fk * W1[k * 10 + j];
    }
    #pragma unroll
    for (int j = 0; j < 10; ++j) h[j] = (h[j] >= 0.f) ? h[j] : 0.1f * h[j];
    float o[10];
    #pragma unroll
    for (int j = 0; j < 10; ++j) o[j] = b2[j];
    #pragma unroll
    for (int k = 0; k < 10; ++k) {
        const float hk = h[k];
        #pragma unroll
        for (int j = 0; j < 10; ++j) o[j] += hk * W2[k * 10 + j];
    }
    float2* po = (float2*)(out + (size_t)e * 10);
    #pragma unroll
    for (int i = 0; i < 5; ++i) { float2 v; v.x = o[2 * i]; v.y = o[2 * i + 1]; po[i] = v; }
}

extern "C" void kernel_launch(void* const* d_in, const int* in_sizes, int n_in,
                              void* d_out, int out_size, void* d_ws, size_t ws_size,
                              hipStream_t stream) {
    const float* x_s      = (const float*)d_in[0];
    const float* x_t      = (const float*)d_in[1];
    const int*   ei       = (const int*)d_in[2];    // (2, E) flat: [src | tgt]
    const float* edge_att = (const float*)d_in[3];
    const float* u        = (const float*)d_in[4];
    const int*   batch_e  = (const int*)d_in[5];
    const float* W1       = (const float*)d_in[6];
    const float* b1       = (const float*)d_in[7];
    const float* W2       = (const float*)d_in[8];
    const float* b2       = (const float*)d_in[9];
    float* out = (float*)d_out;

    const int E   = in_sizes[5];
    const int N_S = in_sizes[0] / 10;
    const int N_T = in_sizes[1] / 5;
    const int blocks = (E + 255) / 256;

    const size_t need = (size_t)N_S * sizeof(Row24) + (size_t)N_T * sizeof(uint4);
    if (ws_size >= need) {
        Row24* As = (Row24*)d_ws;
        uint4* Xt = (uint4*)((char*)d_ws + (size_t)N_S * sizeof(Row24));
        prep_as<<<(N_S + 255) / 256, 256, 0, stream>>>(x_s, W1, As, N_S);
        prep_xt<<<(N_T + 255) / 256, 256, 0, stream>>>(x_t, Xt, N_T);
        edge_mlp_pre<<<blocks, 256, 0, stream>>>(
            As, Xt, ei, ei + E, edge_att, u, batch_e,
            W1, b1, W2, b2, out, E);
    } else {
        edge_mlp_raw<<<blocks, 256, 0, stream>>>(
            x_s, x_t, ei, ei + E, edge_att, u, batch_e,
            W1, b1, W2, b2, out, E);
    }
}